// Round 5
// baseline (250.030 us; speedup 1.0000x reference)
//
#include <hip/hip_runtime.h>
#include <hip/hip_bf16.h>

#define B_   64
#define NW_  256
#define H_   768

#define AB_    (0.1f / 768.0f)   // ALPHA*BETA
#define OMB_   0.9f              // 1 - BETA
#define K1_    0.1f
#define BP_    1.2f
#define AVDL_  50.0f

typedef __bf16 bf16x4 __attribute__((ext_vector_type(4)));
typedef __bf16 bf16x8 __attribute__((ext_vector_type(8)));
typedef float  f32x4  __attribute__((ext_vector_type(4)));

// Workgroup barrier WITHOUT the vmcnt(0) drain __syncthreads() would emit:
// LDS visibility across waves needs only lgkmcnt(0). Prefetch global loads
// stay in flight across the barrier; the compiler's own fine-grained
// vmcnt(N) waits on register uses keep the data deps correct.
#define BAR_LGKM() asm volatile("s_waitcnt lgkmcnt(0)\n\ts_barrier" ::: "memory")

// ---------------------------------------------------------------------------
// 128x128-tile GEMM, fused score-partial epilogue, async-pipelined K-loop.
// Grid: 256 blocks of 256 threads; bid = t*64 + b -> XCD = b%8: all 4 tiles
// of one batch on one XCD (1.57 MB batch slice lives in the 4 MB XCD-L2).
// Wave w computes the 64x64 quadrant (qm=w>>1, qn=w&1) over FULL K=768.
// K-loop: 24 chunks of BK=32; 3-chunk register lookahead; lgkm-only barrier
// so prefetches are never drained at chunk boundaries.
// ---------------------------------------------------------------------------
__global__ __launch_bounds__(256, 1) void gemm_fused(
    const float* __restrict__ q_rep, const float* __restrict__ d_rep,
    const int* __restrict__ q_ids, const int* __restrict__ d_ids,
    const int* __restrict__ d_tfs,
    float* __restrict__ S, float* __restrict__ ws_dot)
{
    // Double-buffered bf16 tiles, rows padded to 40 (80 B stride: 16B-aligned,
    // <=2-way bank aliasing on staging writes = free).
    __shared__ __align__(16) __bf16 As[2][128][40];   // 20 KB
    __shared__ __align__(16) __bf16 Bs[2][128][40];   // 20 KB
    __shared__ float mq_s[128];     // q null mask
    __shared__ float md_s[128];     // d null mask
    __shared__ float mdtf_s[128];   // md * tf

    const int tid  = threadIdx.x;
    const int wave = tid >> 6;
    const int lane = tid & 63;
    const int bid  = blockIdx.x;
    const int b    = bid & 63;
    const int t    = bid >> 6;          // tile 0..3
    const int m0   = (t & 1) * 128;
    const int n0   = (t >> 1) * 128;

    // Masks / md*tf into LDS (visible after the first barrier).
    if (tid < 128) {
        int4 qa = *(const int4*)(q_ids + ((size_t)b * NW_ + m0 + tid) * 4);
        mq_s[tid] = (qa.x == 0 && qa.y == 0 && qa.z == 0 && qa.w == 0) ? 0.f : 1.f;
    } else {
        const int r = tid - 128;
        int4 da = *(const int4*)(d_ids + ((size_t)b * NW_ + n0 + r) * 4);
        float md = (da.x == 0 && da.y == 0 && da.z == 0 && da.w == 0) ? 0.f : 1.f;
        md_s[r]   = md;
        mdtf_s[r] = md * (float)d_tfs[(size_t)b * NW_ + n0 + r];
    }

    // Staging map: chunk = 128 rows x 32 floats. Instr i: thread covers row
    // i*32 + (tid>>3), 16 B segment (tid&7). Lanes 0..7 = one full 128 B
    // line of one row -> 8 fully-used lines per wave instruction.
    const int srow = tid >> 3;          // 0..31
    const int sseg = tid & 7;           // 0..7
    const float* Abase = q_rep + ((size_t)b * NW_ + m0) * H_;
    const float* Bbase = d_rep + ((size_t)b * NW_ + n0) * H_;

    float4 ra[3][4], rb[3][4];          // 3-chunk lookahead slots
    auto loadg = [&](int kc, int s) {
#pragma unroll
        for (int i = 0; i < 4; ++i) {
            const int row = i * 32 + srow;
            ra[s][i] = *(const float4*)(Abase + (size_t)row * H_ + kc * 32 + sseg * 4);
            rb[s][i] = *(const float4*)(Bbase + (size_t)row * H_ + kc * 32 + sseg * 4);
        }
    };
    auto stage = [&](int s, int buf) {
#pragma unroll
        for (int i = 0; i < 4; ++i) {
            const int row = i * 32 + srow;
            bf16x4 va = { (__bf16)ra[s][i].x, (__bf16)ra[s][i].y,
                          (__bf16)ra[s][i].z, (__bf16)ra[s][i].w };
            *(bf16x4*)&As[buf][row][sseg * 4] = va;
            bf16x4 vb = { (__bf16)rb[s][i].x, (__bf16)rb[s][i].y,
                          (__bf16)rb[s][i].z, (__bf16)rb[s][i].w };
            *(bf16x4*)&Bs[buf][row][sseg * 4] = vb;
        }
    };

    f32x4 acc[4][4];
#pragma unroll
    for (int i = 0; i < 4; ++i)
#pragma unroll
        for (int j = 0; j < 4; ++j)
            acc[i][j] = (f32x4){0.f, 0.f, 0.f, 0.f};

    const int fr = lane & 15;
    const int fk = (lane >> 4) * 8;
    const int qm = wave >> 1;           // quadrant row
    const int qn = wave & 1;            // quadrant col

    // Pipeline prologue: 3 chunks in flight, chunk 0 staged.
    loadg(0, 0);
    loadg(1, 1);
    loadg(2, 2);
    stage(0, 0);
    BAR_LGKM();

    // Slot invariant: chunk x lives in slot x%3; slot kc%3 holds chunk kc,
    // already consumed by stage() at the end of iter kc-1 -> safe to refill.
#pragma unroll 6
    for (int kc = 0; kc < 24; ++kc) {
        const int buf = kc & 1;
        if (kc < 21) loadg(kc + 3, kc % 3);      // issue early, ~2 iters of cover
        bf16x8 af[4], bfr[4];
#pragma unroll
        for (int t4 = 0; t4 < 4; ++t4) {
            af[t4]  = *(bf16x8*)&As[buf][qm * 64 + t4 * 16 + fr][fk];
            bfr[t4] = *(bf16x8*)&Bs[buf][qn * 64 + t4 * 16 + fr][fk];
        }
#pragma unroll
        for (int i = 0; i < 4; ++i)
#pragma unroll
            for (int j = 0; j < 4; ++j)
                acc[i][j] = __builtin_amdgcn_mfma_f32_16x16x32_bf16(
                    af[i], bfr[j], acc[i][j], 0, 0, 0);
        if (kc < 23) stage((kc + 1) % 3, buf ^ 1);  // vmcnt(N) wait lands here
        BAR_LGKM();
    }

    // Epilogue: apply masks, store S from acc, reduce score partials in-reg.
    // C layout: col = lane&15, row = (lane>>4)*4 + reg.
    const int cn = lane & 15;
    const int qg = lane >> 4;
    float md_l[4], mdtf_l[4];
#pragma unroll
    for (int j = 0; j < 4; ++j) {
        const int c = qn * 64 + j * 16 + cn;
        md_l[j]   = md_s[c];
        mdtf_l[j] = mdtf_s[c];
    }
    float* Sbase = S + ((size_t)b * NW_ + m0 + qm * 64) * NW_ + n0 + qn * 64;

    float rs[16];
#pragma unroll
    for (int i = 0; i < 4; ++i)
#pragma unroll
        for (int r = 0; r < 4; ++r) {
            const int row = i * 16 + qg * 4 + r;
            const float mq = mq_s[qm * 64 + row];
            float s = 0.f;
#pragma unroll
            for (int j = 0; j < 4; ++j) {
                const float v = acc[i][j][r];
                Sbase[(size_t)row * NW_ + j * 16 + cn] = v * mq * md_l[j];
                s += v * mdtf_l[j];
            }
            rs[i * 4 + r] = s;          // mq applied in final kernel
        }
    // Reduce over the 16 lanes of each quad-group (rows identical there).
#pragma unroll
    for (int off = 1; off <= 8; off <<= 1)
#pragma unroll
        for (int e = 0; e < 16; ++e)
            rs[e] += __shfl_xor(rs[e], off);
    if (cn == 0) {
#pragma unroll
        for (int i = 0; i < 4; ++i)
#pragma unroll
            for (int r = 0; r < 4; ++r)
                atomicAdd(&ws_dot[(size_t)b * NW_ + m0 + qm * 64 + i * 16 + qg * 4 + r],
                          rs[i * 4 + r]);
    }
}

// ---------------------------------------------------------------------------
// Per-batch finisher: exact-match term from ids, BM25 ratio, final reduce.
// 64 blocks x 256 threads; thread t = query window q.
// ---------------------------------------------------------------------------
__global__ __launch_bounds__(256) void final_kernel(
    const float* __restrict__ ws_dot, const int* __restrict__ q_ids,
    const int* __restrict__ d_ids, const int* __restrict__ d_tfs,
    const float* __restrict__ qtw, float* __restrict__ out)
{
    __shared__ int4  dk_s[256];
    __shared__ float tf_s[256];
    __shared__ float red[4];

    const int b = blockIdx.x;
    const int t = threadIdx.x;
    const int wave = t >> 6;
    const int lane = t & 63;

    dk_s[t] = *(const int4*)(d_ids + ((size_t)b * NW_ + t) * 4);
    tf_s[t] = (float)d_tfs[(size_t)b * NW_ + t];
    __syncthreads();

    const int4 qk = *(const int4*)(q_ids + ((size_t)b * NW_ + t) * 4);
    float em = 0.f, dl = 0.f;
    for (int d = 0; d < 256; ++d) {     // dk_s[d]: same addr all lanes -> broadcast
        const int4 dk = dk_s[d];
        const float tf = tf_s[d];
        dl += tf;
        if (dk.x == qk.x && dk.y == qk.y && dk.z == qk.z && dk.w == qk.w)
            em += tf;
    }
    const float mq = (qk.x | qk.y | qk.z | qk.w) ? 1.f : 0.f;
    const float etdf = AB_ * mq * ws_dot[(size_t)b * NW_ + t] + OMB_ * em;
    const float c = K1_ * (1.f - BP_ + BP_ * dl / AVDL_);
    float val = qtw[(size_t)b * NW_ + t] * (etdf * (1.f + K1_)) / (etdf + c + 1e-8f);

#pragma unroll
    for (int off = 32; off; off >>= 1) val += __shfl_xor(val, off);
    if (lane == 0) red[wave] = val;
    __syncthreads();
    if (t == 0) out[b] = red[0] + red[1] + red[2] + red[3];
}

extern "C" void kernel_launch(void* const* d_in, const int* in_sizes, int n_in,
                              void* d_out, int out_size, void* d_ws, size_t ws_size,
                              hipStream_t stream)
{
    const float* q_rep = (const float*)d_in[0];
    const float* d_rep = (const float*)d_in[1];
    const float* qtw   = (const float*)d_in[2];
    const int*   q_ids = (const int*)d_in[3];
    const int*   d_ids = (const int*)d_in[4];
    const int*   d_tfs = (const int*)d_in[5];

    float* out = (float*)d_out;
    float* S   = out + B_;              // d_expanded_tf, [B, NW, NW]
    float* ws_dot = (float*)d_ws;       // [B, NW] f32

    hipMemsetAsync(ws_dot, 0, (size_t)B_ * NW_ * sizeof(float), stream);

    gemm_fused<<<256, 256, 0, stream>>>(q_rep, d_rep, q_ids, d_ids, d_tfs,
                                        S, ws_dot);
    final_kernel<<<B_, 256, 0, stream>>>(ws_dot, q_ids, d_ids, d_tfs, qtw, out);
}

// Round 6
// 147.169 us; speedup vs baseline: 1.6989x; 1.6989x over previous
//
#include <hip/hip_runtime.h>
#include <hip/hip_bf16.h>

#define B_   64
#define NW_  256
#define H_   768

#define AB_    (0.1f / 768.0f)   // ALPHA*BETA
#define OMB_   0.9f              // 1 - BETA
#define K1_    0.1f
#define BP_    1.2f
#define AVDL_  50.0f

typedef __bf16 bf16x4 __attribute__((ext_vector_type(4)));
typedef __bf16 bf16x8 __attribute__((ext_vector_type(8)));
typedef float  f32x4  __attribute__((ext_vector_type(4)));

// Workgroup barrier WITHOUT the vmcnt(0) drain __syncthreads() emits:
// LDS visibility across waves needs only lgkmcnt(0). VGPR-destined global
// prefetch loads stay in flight across the barrier; the compiler's
// fine-grained vmcnt(N) waits on register uses keep data deps correct.
#define BAR_LGKM() asm volatile("s_waitcnt lgkmcnt(0)\n\ts_barrier" ::: "memory")

// ---------------------------------------------------------------------------
// 128x128-tile GEMM, fused score epilogue (dot + exact-match), pipelined.
// Grid: 256 blocks of 256 threads; bid = t*64 + b -> XCD = b%8: all 4 tiles
// of one batch on one XCD (batch slice lives in the 4 MB XCD-L2).
// Wave w computes the 64x64 quadrant (qm=w>>1, qn=w&1) over FULL K=768.
// K-loop: 24 chunks of BK=32, FULLY unrolled (all slot/buf indices literal
// -> no scratch spill, cf. R5), depth-3 static register lookahead,
// lgkm-only barriers so prefetches never drain at chunk boundaries.
// ---------------------------------------------------------------------------
__global__ __launch_bounds__(256, 1) void gemm_fused(
    const float* __restrict__ q_rep, const float* __restrict__ d_rep,
    const int* __restrict__ q_ids, const int* __restrict__ d_ids,
    const int* __restrict__ d_tfs,
    float* __restrict__ S, float* __restrict__ ws_etdf)
{
    // Padded rows (40 bf16 = 80 B stride): 16B-aligned, <=2-way bank alias.
    __shared__ __align__(16) __bf16 As[2][128][40];   // 20 KB
    __shared__ __align__(16) __bf16 Bs[2][128][40];   // 20 KB
    __shared__ float mq_s[128];     // q null mask
    __shared__ float md_s[128];     // d null mask
    __shared__ float mdtf_s[128];   // md * tf
    __shared__ float tf_s[128];     // raw tf (em term is unmasked)
    __shared__ int4  qk_s[128];     // q id keys
    __shared__ int4  dk_s[128];     // d id keys

    const int tid  = threadIdx.x;
    const int wave = tid >> 6;
    const int lane = tid & 63;
    const int bid  = blockIdx.x;
    const int b    = bid & 63;
    const int t    = bid >> 6;          // tile 0..3
    const int m0   = (t & 1) * 128;
    const int n0   = (t >> 1) * 128;

    // Masks / keys / tf into LDS (visible after the first barrier).
    if (tid < 128) {
        int4 qa = *(const int4*)(q_ids + ((size_t)b * NW_ + m0 + tid) * 4);
        qk_s[tid] = qa;
        mq_s[tid] = (qa.x == 0 && qa.y == 0 && qa.z == 0 && qa.w == 0) ? 0.f : 1.f;
    } else {
        const int r = tid - 128;
        int4 da = *(const int4*)(d_ids + ((size_t)b * NW_ + n0 + r) * 4);
        dk_s[r] = da;
        float md = (da.x == 0 && da.y == 0 && da.z == 0 && da.w == 0) ? 0.f : 1.f;
        float tf = (float)d_tfs[(size_t)b * NW_ + n0 + r];
        md_s[r]   = md;
        tf_s[r]   = tf;
        mdtf_s[r] = md * tf;
    }

    // Staging map: chunk = 128 rows x 32 floats. Instr i: thread covers row
    // i*32 + (tid>>3), 16 B segment (tid&7): 8 fully-used 128 B lines/inst.
    const int srow = tid >> 3;          // 0..31
    const int sseg = tid & 7;           // 0..7
    const float* Abase = q_rep + ((size_t)b * NW_ + m0) * H_;
    const float* Bbase = d_rep + ((size_t)b * NW_ + n0) * H_;

    // Three STATIC lookahead slots — only ever indexed by literals.
    float4 ra0[4], rb0[4], ra1[4], rb1[4], ra2[4], rb2[4];

    auto loadg = [&](float4 (&ra)[4], float4 (&rb)[4], int kc) {
#pragma unroll
        for (int i = 0; i < 4; ++i) {
            const int row = i * 32 + srow;
            ra[i] = *(const float4*)(Abase + (size_t)row * H_ + kc * 32 + sseg * 4);
            rb[i] = *(const float4*)(Bbase + (size_t)row * H_ + kc * 32 + sseg * 4);
        }
    };
    auto stage = [&](float4 (&ra)[4], float4 (&rb)[4], int buf) {
#pragma unroll
        for (int i = 0; i < 4; ++i) {
            const int row = i * 32 + srow;
            bf16x4 va = { (__bf16)ra[i].x, (__bf16)ra[i].y,
                          (__bf16)ra[i].z, (__bf16)ra[i].w };
            *(bf16x4*)&As[buf][row][sseg * 4] = va;
            bf16x4 vb = { (__bf16)rb[i].x, (__bf16)rb[i].y,
                          (__bf16)rb[i].z, (__bf16)rb[i].w };
            *(bf16x4*)&Bs[buf][row][sseg * 4] = vb;
        }
    };

    f32x4 acc[4][4];
#pragma unroll
    for (int i = 0; i < 4; ++i)
#pragma unroll
        for (int j = 0; j < 4; ++j)
            acc[i][j] = (f32x4){0.f, 0.f, 0.f, 0.f};

    const int fr = lane & 15;
    const int fk = (lane >> 4) * 8;
    const int qm = wave >> 1;           // quadrant row
    const int qn = wave & 1;            // quadrant col

    // Pipeline prologue: 3 chunks in flight, chunk 0 staged.
    loadg(ra0, rb0, 0);
    loadg(ra1, rb1, 1);
    loadg(ra2, rb2, 2);
    stage(ra0, rb0, 0);
    BAR_LGKM();

    // Invariant: chunk x lives in slot x%3; slot kc%3 (chunk kc) was staged
    // at the end of iter kc-1 -> free to refill with chunk kc+3.
#pragma unroll
    for (int kc = 0; kc < 24; ++kc) {
        const int buf = kc & 1;
        if (kc < 21) {
            if (kc % 3 == 0)      loadg(ra0, rb0, kc + 3);
            else if (kc % 3 == 1) loadg(ra1, rb1, kc + 3);
            else                  loadg(ra2, rb2, kc + 3);
        }
        bf16x8 af[4], bfr[4];
#pragma unroll
        for (int t4 = 0; t4 < 4; ++t4) {
            af[t4]  = *(bf16x8*)&As[buf][qm * 64 + t4 * 16 + fr][fk];
            bfr[t4] = *(bf16x8*)&Bs[buf][qn * 64 + t4 * 16 + fr][fk];
        }
#pragma unroll
        for (int i = 0; i < 4; ++i)
#pragma unroll
            for (int j = 0; j < 4; ++j)
                acc[i][j] = __builtin_amdgcn_mfma_f32_16x16x32_bf16(
                    af[i], bfr[j], acc[i][j], 0, 0, 0);
        if (kc < 23) {
            const int nb = buf ^ 1;
            if ((kc + 1) % 3 == 0)      stage(ra0, rb0, nb);
            else if ((kc + 1) % 3 == 1) stage(ra1, rb1, nb);
            else                        stage(ra2, rb2, nb);
        }
        BAR_LGKM();
    }

    // Epilogue. C layout: col = lane&15, row = (lane>>4)*4 + reg.
    // etdf contribution per (row, col): AB*mq*md*v*tf + 0.9*em*tf.
    const int cn = lane & 15;
    const int qg = lane >> 4;
    float md_l[4], mdtf_l[4], tf_l[4];
    int4  dk_l[4];
#pragma unroll
    for (int j = 0; j < 4; ++j) {
        const int c = qn * 64 + j * 16 + cn;
        md_l[j]   = md_s[c];
        mdtf_l[j] = mdtf_s[c];
        tf_l[j]   = tf_s[c];
        dk_l[j]   = dk_s[c];
    }
    float* Sbase = S + ((size_t)b * NW_ + m0 + qm * 64) * NW_ + n0 + qn * 64;

    float rs[16];
#pragma unroll
    for (int i = 0; i < 4; ++i)
#pragma unroll
        for (int r = 0; r < 4; ++r) {
            const int row = i * 16 + qg * 4 + r;
            const float mq = mq_s[qm * 64 + row];
            const int4  qk = qk_s[qm * 64 + row];
            float sdot = 0.f, sem = 0.f;
#pragma unroll
            for (int j = 0; j < 4; ++j) {
                const float v = acc[i][j][r];
                Sbase[(size_t)row * NW_ + j * 16 + cn] = v * mq * md_l[j];
                sdot += v * mdtf_l[j];
                const int4 dk = dk_l[j];
                if (dk.x == qk.x && dk.y == qk.y && dk.z == qk.z && dk.w == qk.w)
                    sem += tf_l[j];
            }
            rs[i * 4 + r] = mq * AB_ * sdot + OMB_ * sem;
        }
    // Reduce over the 16 lanes of each quad-group (rows identical there).
#pragma unroll
    for (int off = 1; off <= 8; off <<= 1)
#pragma unroll
        for (int e = 0; e < 16; ++e)
            rs[e] += __shfl_xor(rs[e], off);
    if (cn == 0) {
#pragma unroll
        for (int i = 0; i < 4; ++i)
#pragma unroll
            for (int r = 0; r < 4; ++r)
                atomicAdd(&ws_etdf[(size_t)b * NW_ + m0 + qm * 64 + i * 16 + qg * 4 + r],
                          rs[i * 4 + r]);
    }
}

// ---------------------------------------------------------------------------
// Final: per batch, dl = sum(tf); dtw = 1.1*etdf/(etdf + K1*(1-Bp+Bp*dl/AVDL)
// + 1e-8); s[b] = sum_q qtw*dtw.  One wave per batch.
// ---------------------------------------------------------------------------
__global__ __launch_bounds__(64) void final_kernel(
    const float* __restrict__ ws_etdf, const int* __restrict__ d_tfs,
    const float* __restrict__ qtw, float* __restrict__ out)
{
    const int b = blockIdx.x;
    const int lane = threadIdx.x;

    float4 ev = *(const float4*)(ws_etdf + (size_t)b * NW_ + lane * 4);
    int4  tf4 = *(const int4*)(d_tfs   + (size_t)b * NW_ + lane * 4);
    float4 qv = *(const float4*)(qtw    + (size_t)b * NW_ + lane * 4);

    float dl = (float)(tf4.x + tf4.y + tf4.z + tf4.w);
#pragma unroll
    for (int off = 32; off; off >>= 1) dl += __shfl_xor(dl, off);

    const float c = K1_ * (1.f - BP_ + BP_ * dl / AVDL_);
    float ew[4] = {ev.x, ev.y, ev.z, ev.w};
    float qw[4] = {qv.x, qv.y, qv.z, qv.w};
    float s = 0.f;
#pragma unroll
    for (int j = 0; j < 4; ++j)
        s += qw[j] * (ew[j] * (1.f + K1_)) / (ew[j] + c + 1e-8f);
#pragma unroll
    for (int off = 32; off; off >>= 1) s += __shfl_xor(s, off);
    if (lane == 0) out[b] = s;
}

extern "C" void kernel_launch(void* const* d_in, const int* in_sizes, int n_in,
                              void* d_out, int out_size, void* d_ws, size_t ws_size,
                              hipStream_t stream)
{
    const float* q_rep = (const float*)d_in[0];
    const float* d_rep = (const float*)d_in[1];
    const float* qtw   = (const float*)d_in[2];
    const int*   q_ids = (const int*)d_in[3];
    const int*   d_ids = (const int*)d_in[4];
    const int*   d_tfs = (const int*)d_in[5];

    float* out = (float*)d_out;
    float* S   = out + B_;              // d_expanded_tf, [B, NW, NW]
    float* ws_etdf = (float*)d_ws;      // [B, NW] f32

    hipMemsetAsync(ws_etdf, 0, (size_t)B_ * NW_ * sizeof(float), stream);

    gemm_fused<<<256, 256, 0, stream>>>(q_rep, d_rep, q_ids, d_ids, d_tfs,
                                        S, ws_etdf);
    final_kernel<<<B_, 64, 0, stream>>>(ws_etdf, d_tfs, qtw, out);
}